// Round 1
// baseline (101.279 us; speedup 1.0000x reference)
//
#include <hip/hip_runtime.h>
#include <math.h>

// Problem constants (from reference setup_inputs): x [32,1024,64,64] f32
constexpr int B_ = 32;
constexpr int C_ = 1024;
constexpr int HW = 64 * 64;          // 4096 spatial per batch
constexpr int NSPATIAL = B_ * HW;    // 131072 total positions
constexpr int BLOCK = 256;
constexpr int TILE = 1024;           // spatial positions per block (256 thr x float4)
constexpr int NTILES = NSPATIAL / TILE;  // 128 spatial tiles

// Kernel 1: partial dot over a channel chunk for a spatial tile.
// Coalesced: lane i reads x[b, c, hw0 + 4*i .. +3] as float4 (16B/lane).
__global__ __launch_bounds__(BLOCK) void k_dot(
    const float4* __restrict__ x4, const float* __restrict__ w,
    float4* __restrict__ part4, int cpc /* channels per chunk */) {
    __shared__ float ws[1024];
    const int tile  = blockIdx.x;   // 0..NTILES-1
    const int chunk = blockIdx.y;
    const int c0    = chunk * cpc;
    const int t     = threadIdx.x;

    for (int c = t; c < cpc; c += BLOCK) ws[c] = w[c0 + c];
    __syncthreads();

    const int b   = tile >> 2;                    // 4 tiles per batch image
    const int hw4 = (tile & 3) * (TILE / 4) + t;  // float4 index within batch plane
    const float4* p = x4 + (size_t)(b * C_ + c0) * (HW / 4) + hw4;

    float4 acc = make_float4(0.f, 0.f, 0.f, 0.f);
    #pragma unroll 4
    for (int c = 0; c < cpc; ++c) {
        float4 v = p[(size_t)c * (HW / 4)];
        float wc = ws[c];
        acc.x += wc * v.x;
        acc.y += wc * v.y;
        acc.z += wc * v.z;
        acc.w += wc * v.w;
    }
    part4[(size_t)chunk * (NSPATIAL / 4) + (size_t)tile * (TILE / 4) + t] = acc;
}

// Kernel 2: combine chunk partials, bias + sigmoid + softplus - z*y, block-reduce.
__global__ __launch_bounds__(BLOCK) void k_finish(
    const float4* __restrict__ part4, const float* __restrict__ bias,
    const int* __restrict__ mode, float* __restrict__ blocksum, int nchunks) {
    const int t   = threadIdx.x;
    const int idx = blockIdx.x * BLOCK + t;  // float4 index, 32768 total -> 128 blocks

    float4 s = make_float4(0.f, 0.f, 0.f, 0.f);
    for (int k = 0; k < nchunks; ++k) {
        float4 v = part4[(size_t)k * (NSPATIAL / 4) + idx];
        s.x += v.x; s.y += v.y; s.z += v.z; s.w += v.w;
    }
    const float bb = bias[0];
    const float y  = (float)mode[0];

    float vals[4] = {s.x, s.y, s.z, s.w};
    float local = 0.f;
    #pragma unroll
    for (int j = 0; j < 4; ++j) {
        float logit = vals[j] + bb;
        float z  = 1.f / (1.f + __expf(-logit));       // sigmoid
        float pe = log1pf(__expf(z)) - z * y;          // softplus(z) - z*y
        local += pe;
    }

    __shared__ float red[BLOCK];
    red[t] = local;
    __syncthreads();
    for (int off = BLOCK / 2; off > 0; off >>= 1) {
        if (t < off) red[t] += red[t + off];
        __syncthreads();
    }
    if (t == 0) blocksum[blockIdx.x] = red[0];
}

// Kernel 3: final deterministic reduce of 128 block sums -> mean.
__global__ __launch_bounds__(128) void k_final(
    const float* __restrict__ blocksum, float* __restrict__ out) {
    __shared__ float red[128];
    const int t = threadIdx.x;
    red[t] = blocksum[t];
    __syncthreads();
    for (int off = 64; off > 0; off >>= 1) {
        if (t < off) red[t] += red[t + off];
        __syncthreads();
    }
    if (t == 0) out[0] = red[0] / (float)NSPATIAL;
}

extern "C" void kernel_launch(void* const* d_in, const int* in_sizes, int n_in,
                              void* d_out, int out_size, void* d_ws, size_t ws_size,
                              hipStream_t stream) {
    const float4* x4  = (const float4*)d_in[0];
    const float*  w   = (const float*)d_in[1];
    const float*  bia = (const float*)d_in[2];
    const int*    mod = (const int*)d_in[3];
    float* out = (float*)d_out;

    // Pick channel-chunk count based on available workspace:
    // need nchunks * NSPATIAL * 4 bytes for partials + 128*4 for block sums.
    int nchunks = 8;
    while (nchunks > 1 &&
           (size_t)nchunks * NSPATIAL * sizeof(float) + 128 * sizeof(float) > ws_size)
        nchunks >>= 1;
    const int cpc = C_ / nchunks;

    float4* part4    = (float4*)d_ws;
    float*  blocksum = (float*)((char*)d_ws + (size_t)nchunks * NSPATIAL * sizeof(float));

    dim3 grid1(NTILES, nchunks);
    k_dot<<<grid1, BLOCK, 0, stream>>>(x4, w, part4, cpc);
    k_finish<<<NSPATIAL / 4 / BLOCK, BLOCK, 0, stream>>>(part4, bia, mod, blocksum, nchunks);
    k_final<<<1, 128, 0, stream>>>(blocksum, out);
}

// Round 2
// 97.353 us; speedup vs baseline: 1.0403x; 1.0403x over previous
//
#include <hip/hip_runtime.h>
#include <math.h>

// x [32,1024,64,64] f32, w [1,1024], b [1], mode scalar int.
constexpr int B_ = 32;
constexpr int C_ = 1024;
constexpr int HW = 64 * 64;           // 4096 spatial per batch (1024 float4)
constexpr int NSPATIAL = B_ * HW;     // 131072
constexpr int BLOCK = 256;
constexpr int PX_PER_BLOCK = 256;     // 64 lanes x 4 px; all 4 waves share pixels
constexpr int NBLOCKS = NSPATIAL / PX_PER_BLOCK;  // 512

// Fused: dot over all 1024 channels (split 256/wave), LDS-combine, bias +
// sigmoid + softplus - z*y, block-reduce -> blocksum[block].
__global__ __launch_bounds__(BLOCK) void k_main(
    const float4* __restrict__ x4, const float4* __restrict__ w4g,
    const float* __restrict__ bias, const int* __restrict__ mode,
    float* __restrict__ blocksum) {
    __shared__ float4 w4[C_ / 4];     // 1024 weights
    __shared__ float4 red[BLOCK];

    const int t    = threadIdx.x;
    const int wv   = t >> 6;          // wave 0..3 -> channel quarter
    const int lane = t & 63;

    w4[t] = w4g[t];
    __syncthreads();

    const int blk = blockIdx.x;       // 0..511
    const int b   = blk >> 4;         // 16 tiles per batch image
    const int hw4 = (blk & 15) * 64 + lane;  // float4 index in 4096-px plane

    // base: channel wv*256 of batch b
    const float4* p = x4 + ((size_t)(b * C_ + wv * 256) * (HW / 4)) + hw4;

    float4 acc = make_float4(0.f, 0.f, 0.f, 0.f);
    #pragma unroll 4
    for (int kk = 0; kk < 64; ++kk) {
        float4 wc = w4[wv * 64 + kk];     // 4 consecutive channel weights
        float4 v0 = p[(size_t)(4 * kk + 0) * (HW / 4)];
        float4 v1 = p[(size_t)(4 * kk + 1) * (HW / 4)];
        float4 v2 = p[(size_t)(4 * kk + 2) * (HW / 4)];
        float4 v3 = p[(size_t)(4 * kk + 3) * (HW / 4)];
        acc.x += wc.x * v0.x + wc.y * v1.x + wc.z * v2.x + wc.w * v3.x;
        acc.y += wc.x * v0.y + wc.y * v1.y + wc.z * v2.y + wc.w * v3.y;
        acc.z += wc.x * v0.z + wc.y * v1.z + wc.z * v2.z + wc.w * v3.z;
        acc.w += wc.x * v0.w + wc.y * v1.w + wc.z * v2.w + wc.w * v3.w;
    }

    red[t] = acc;
    __syncthreads();

    if (t < 64) {
        float4 a0 = red[t], a1 = red[t + 64], a2 = red[t + 128], a3 = red[t + 192];
        const float bb = bias[0];
        const float y  = (float)mode[0];
        float logit[4] = {a0.x + a1.x + a2.x + a3.x,
                          a0.y + a1.y + a2.y + a3.y,
                          a0.z + a1.z + a2.z + a3.z,
                          a0.w + a1.w + a2.w + a3.w};
        float local = 0.f;
        #pragma unroll
        for (int j = 0; j < 4; ++j) {
            float lg = logit[j] + bb;
            float z  = 1.f / (1.f + __expf(-lg));      // sigmoid
            local   += log1pf(__expf(z)) - z * y;      // softplus(z) - z*y
        }
        // deterministic wave-level tree reduce over 64 lanes
        #pragma unroll
        for (int off = 32; off > 0; off >>= 1)
            local += __shfl_down(local, off, 64);
        if (lane == 0) blocksum[blk] = local;
    }
}

// Final deterministic reduce of 512 block sums -> mean.
__global__ __launch_bounds__(512) void k_final(
    const float* __restrict__ blocksum, float* __restrict__ out) {
    __shared__ float red[512];
    const int t = threadIdx.x;
    red[t] = blocksum[t];
    __syncthreads();
    for (int off = 256; off > 0; off >>= 1) {
        if (t < off) red[t] += red[t + off];
        __syncthreads();
    }
    if (t == 0) out[0] = red[0] / (float)NSPATIAL;
}

extern "C" void kernel_launch(void* const* d_in, const int* in_sizes, int n_in,
                              void* d_out, int out_size, void* d_ws, size_t ws_size,
                              hipStream_t stream) {
    const float4* x4  = (const float4*)d_in[0];
    const float4* w4g = (const float4*)d_in[1];
    const float*  bia = (const float*)d_in[2];
    const int*    mod = (const int*)d_in[3];
    float* out = (float*)d_out;

    float* blocksum = (float*)d_ws;   // 512 floats

    k_main<<<NBLOCKS, BLOCK, 0, stream>>>(x4, w4g, bia, mod, blocksum);
    k_final<<<1, 512, 0, stream>>>(blocksum, out);
}